// Round 2
// baseline (561.432 us; speedup 1.0000x reference)
//
#include <hip/hip_runtime.h>

typedef __attribute__((ext_vector_type(8))) short short8;
typedef __attribute__((ext_vector_type(4))) float floatx4;
typedef __attribute__((ext_vector_type(4))) unsigned int uintx4;

__device__ __forceinline__ short f2bf(float f) {
    unsigned u = __builtin_bit_cast(unsigned, f);
    u = (u + 0x7FFFu + ((u >> 16) & 1u)) >> 16;
    return (short)u;
}

// ---------------------------------------------------------------------------
// Workspace layout (bf16 elements):
//   w1T0=0, w1T1=65536, w1T2=196608, w2T0=458752, w2T1=524288, w2T2=589824
//   xg base = 655360:  xg0 @ +0 (4096x256), xg1 @ +1048576 (4096x512),
//                      xg2 @ +3145728 (4096x1024).  Total 15.99 MB.
// ---------------------------------------------------------------------------

__global__ __launch_bounds__(256) void prep_w(
    const float* __restrict__ w10, const float* __restrict__ w11, const float* __restrict__ w12,
    const float* __restrict__ w20, const float* __restrict__ w21, const float* __restrict__ w22,
    unsigned short* __restrict__ wsb)
{
    __shared__ float tile[32][33];
    int blk = blockIdx.x;
    const float* in; unsigned short* out; int K, t0;
    if (blk < 64)       { in = w10; out = wsb;          K = 256;  t0 = 0; }
    else if (blk < 192) { in = w11; out = wsb + 65536;  K = 512;  t0 = 64; }
    else if (blk < 448) { in = w12; out = wsb + 196608; K = 1024; t0 = 192; }
    else if (blk < 512) { in = w20; out = wsb + 458752; K = 256;  t0 = 448; }
    else if (blk < 576) { in = w21; out = wsb + 524288; K = 256;  t0 = 512; }
    else                { in = w22; out = wsb + 589824; K = 256;  t0 = 576; }
    int tile_id = blk - t0;
    int tk = K >> 5;
    int k0 = (tile_id % tk) << 5;
    int n0 = (tile_id / tk) << 5;
    int t = threadIdx.x;
    int j = t & 31, i0 = (t >> 5) << 2;
    #pragma unroll
    for (int u = 0; u < 4; u++)
        tile[i0 + u][j] = in[(size_t)(k0 + i0 + u) * 256 + (n0 + j)];
    __syncthreads();
    int kf = t & 31, nf0 = (t >> 5) << 2;
    #pragma unroll
    for (int u = 0; u < 4; u++)
        out[(size_t)(n0 + nf0 + u) * K + (k0 + kf)] = (unsigned short)f2bf(tile[kf][nf0 + u]);
}

// ---------------------------------------------------------------------------
// Massively-parallel gather: one thread = one (row, 8-channel chunk).
// 3584 blocks x 256 threads; 8 independent strided loads/thread, one 16B
// coalesced bf16 store. No LDS, no barriers -> latency fully overlapped.
// ---------------------------------------------------------------------------
__global__ __launch_bounds__(256) void gather_x(
    const float* __restrict__ f0, const float* __restrict__ f1, const float* __restrict__ f2,
    const int* __restrict__ p0, const int* __restrict__ p1, const int* __restrict__ p2,
    unsigned short* __restrict__ xg)
{
    int blk = blockIdx.x;
    const float* feat; const int* pid; int C, HW, sh; unsigned short* dst;
    if (blk < 512)        { feat = f0; pid = p0; C = 256;  HW = 16384; sh = 5; dst = xg; }
    else if (blk < 1536)  { feat = f1; pid = p1; C = 512;  HW = 4096;  sh = 6; dst = xg + 1048576; blk -= 512; }
    else                  { feat = f2; pid = p2; C = 1024; HW = 1024;  sh = 7; dst = xg + 3145728; blk -= 1536; }

    int q   = (blk << 8) + threadIdx.x;
    int row = q >> sh;                       // 0..4095
    int c0  = (q & ((1 << sh) - 1)) << 3;    // channel chunk start
    int b   = row >> 8, pp = row & 255;
    int s   = pid[pp];
    const float* src = feat + ((size_t)b * C + c0) * HW + s;

    float v[8];
    #pragma unroll
    for (int j = 0; j < 8; j++) v[j] = src[(size_t)j * HW];
    short8 sv;
    #pragma unroll
    for (int j = 0; j < 8; j++) sv[j] = f2bf(v[j]);
    *(short8*)(dst + (size_t)row * C + c0) = sv;
}

// ---------------------------------------------------------------------------
// Dense fused MLP + L2-normalize, reading pre-gathered xg (contiguous).
// Block: 32 rows x 256 cols. 4 waves: wave w -> rows (w&1)*16, cols (w>>1)*128.
// GEMM1 A-fragments read directly from global xg (L2/IC resident, 16B/lane).
// LDS: wsS [256][72] bf16 = 36864 @ 0, hs [32][264] bf16 = 16896 @ 18432(el),
//      rs [32] f32 @ 26880(el).  54,272 B -> 2 blocks/CU.
// ---------------------------------------------------------------------------
__global__ __launch_bounds__(256) void mlp(
    const float* __restrict__ b1_0, const float* __restrict__ b1_1, const float* __restrict__ b1_2,
    const float* __restrict__ b2_0, const float* __restrict__ b2_1, const float* __restrict__ b2_2,
    const unsigned short* __restrict__ wsb,
    float* __restrict__ out)
{
    __shared__ __align__(16) unsigned short smem[26944];
    unsigned short* wsS = smem;            // 256*72
    unsigned short* hs  = smem + 18432;    // 32*264
    float* rs = (float*)(smem + 26880);    // 32 floats

    int blk = blockIdx.x;
    int scale = 2 - (blk >> 7);            // big-K blocks dispatched first
    int mblk = blk & 127;

    const float* b1; const float* b2;
    const unsigned short* w1T; const unsigned short* w2T; const unsigned short* xg;
    int C; size_t outBase;
    if (scale == 0)      { b1 = b1_0; b2 = b2_0; w1T = wsb;          w2T = wsb + 458752;
                           xg = wsb + 655360;           C = 256;  outBase = 0; }
    else if (scale == 1) { b1 = b1_1; b2 = b2_1; w1T = wsb + 65536;  w2T = wsb + 524288;
                           xg = wsb + 655360 + 1048576; C = 512;  outBase = 1048576; }
    else                 { b1 = b1_2; b2 = b2_2; w1T = wsb + 196608; w2T = wsb + 589824;
                           xg = wsb + 655360 + 3145728; C = 1024; outBase = 2097152; }

    int t = threadIdx.x;
    int wid = t >> 6, lane = t & 63, quad = lane >> 4, l15 = lane & 15;
    int r0 = (wid & 1) << 4;          // row offset of this wave
    int c0 = (wid >> 1) << 7;         // col offset of this wave

    floatx4 acc[8];
    #pragma unroll
    for (int f = 0; f < 8; f++) acc[f] = (floatx4){0.f, 0.f, 0.f, 0.f};

    // A-fragment source: global xg row for this lane
    const unsigned short* aG = xg + (size_t)((mblk << 5) + r0 + l15) * C;

    // ---------------- GEMM1: x[32,C] @ w1[C,256] ----------------
    for (int kc = 0; kc < C; kc += 64) {
        // stage w1T chunk: thread t = row n, 128B contiguous
        {
            const uintx4* src = (const uintx4*)(w1T + (size_t)t * C + kc);
            uintx4* dst = (uintx4*)(wsS + t * 72);
            #pragma unroll
            for (int j2 = 0; j2 < 8; j2++) dst[j2] = src[j2];
        }
        __syncthreads();
        const unsigned short* bRow = wsS + (c0 + l15) * 72;
        #pragma unroll
        for (int ks = 0; ks < 2; ks++) {
            short8 af = *(const short8*)(aG + kc + ks * 32 + quad * 8);
            #pragma unroll
            for (int f = 0; f < 8; f++) {
                short8 bf = *(const short8*)(bRow + f * (16 * 72) + ks * 32 + quad * 8);
                acc[f] = __builtin_amdgcn_mfma_f32_16x16x32_bf16(af, bf, acc[f], 0, 0, 0);
            }
        }
        __syncthreads();
    }

    // ---------------- h = relu(acc + b1) -> LDS (bf16) ----------------
    {
        float bias1[8];
        #pragma unroll
        for (int f = 0; f < 8; f++) bias1[f] = b1[c0 + f * 16 + l15];
        #pragma unroll
        for (int f = 0; f < 8; f++)
            #pragma unroll
            for (int reg = 0; reg < 4; reg++) {
                float h = fmaxf(acc[f][reg] + bias1[f], 0.f);
                hs[(r0 + quad * 4 + reg) * 264 + (c0 + f * 16 + l15)] = (unsigned short)f2bf(h);
            }
    }

    // ---------------- GEMM2: h[32,256] @ w2[256,256] ----------------
    #pragma unroll
    for (int f = 0; f < 8; f++) acc[f] = (floatx4){0.f, 0.f, 0.f, 0.f};
    const unsigned short* hA = hs + (r0 + l15) * 264;
    for (int kc = 0; kc < 256; kc += 64) {
        {
            const uintx4* src = (const uintx4*)(w2T + (size_t)t * 256 + kc);
            uintx4* dst = (uintx4*)(wsS + t * 72);
            #pragma unroll
            for (int j2 = 0; j2 < 8; j2++) dst[j2] = src[j2];
        }
        __syncthreads();
        const unsigned short* bRow = wsS + (c0 + l15) * 72;
        #pragma unroll
        for (int ks = 0; ks < 2; ks++) {
            short8 af = *(const short8*)(hA + kc + ks * 32 + quad * 8);
            #pragma unroll
            for (int f = 0; f < 8; f++) {
                short8 bf = *(const short8*)(bRow + f * (16 * 72) + ks * 32 + quad * 8);
                acc[f] = __builtin_amdgcn_mfma_f32_16x16x32_bf16(af, bf, acc[f], 0, 0, 0);
            }
        }
        __syncthreads();
    }

    // ---------------- epilogue: y = acc + b2; y / (||y|| + 1e-7) ----------------
    {
        float bias2[8];
        #pragma unroll
        for (int f = 0; f < 8; f++) bias2[f] = b2[c0 + f * 16 + l15];
        float psq[4] = {0.f, 0.f, 0.f, 0.f};
        #pragma unroll
        for (int f = 0; f < 8; f++)
            #pragma unroll
            for (int reg = 0; reg < 4; reg++) {
                float yv = acc[f][reg] + bias2[f];
                acc[f][reg] = yv;
                psq[reg] += yv * yv;
            }
        #pragma unroll
        for (int m = 1; m < 16; m <<= 1)
            #pragma unroll
            for (int reg = 0; reg < 4; reg++)
                psq[reg] += __shfl_xor(psq[reg], m, 16);

        if (t < 32) rs[t] = 0.f;
        __syncthreads();
        if (l15 == 0) {
            #pragma unroll
            for (int reg = 0; reg < 4; reg++)
                atomicAdd(&rs[r0 + quad * 4 + reg], psq[reg]);
        }
        __syncthreads();

        #pragma unroll
        for (int f = 0; f < 8; f++)
            #pragma unroll
            for (int reg = 0; reg < 4; reg++) {
                int row = r0 + quad * 4 + reg;
                float inv = 1.f / (sqrtf(rs[row]) + 1e-7f);
                out[outBase + (size_t)((mblk << 5) + row) * 256 + (c0 + f * 16 + l15)] =
                    acc[f][reg] * inv;
            }
    }
}

extern "C" void kernel_launch(void* const* d_in, const int* in_sizes, int n_in,
                              void* d_out, int out_size, void* d_ws, size_t ws_size,
                              hipStream_t stream)
{
    (void)n_in; (void)out_size; (void)ws_size;
    bool dict = (in_sizes[1] == 256);
    const float *feat[3], *w1[3], *b1[3], *w2[3], *b2[3];
    const int* pid[3];
    for (int i = 0; i < 3; i++) {
        if (dict) {
            feat[i] = (const float*)d_in[i * 6 + 0];
            pid[i]  = (const int*)  d_in[i * 6 + 1];
            w1[i]   = (const float*)d_in[i * 6 + 2];
            b1[i]   = (const float*)d_in[i * 6 + 3];
            w2[i]   = (const float*)d_in[i * 6 + 4];
            b2[i]   = (const float*)d_in[i * 6 + 5];
        } else {
            feat[i] = (const float*)d_in[i];
            pid[i]  = (const int*)  d_in[3 + i];
            w1[i]   = (const float*)d_in[6 + 4 * i + 0];
            b1[i]   = (const float*)d_in[6 + 4 * i + 1];
            w2[i]   = (const float*)d_in[6 + 4 * i + 2];
            b2[i]   = (const float*)d_in[6 + 4 * i + 3];
        }
    }
    unsigned short* wsb = (unsigned short*)d_ws;
    gather_x<<<3584, 256, 0, stream>>>(feat[0], feat[1], feat[2],
                                       pid[0], pid[1], pid[2],
                                       wsb + 655360);
    prep_w<<<640, 256, 0, stream>>>(w1[0], w1[1], w1[2], w2[0], w2[1], w2[2], wsb);
    mlp<<<384, 256, 0, stream>>>(b1[0], b1[1], b1[2],
                                 b2[0], b2[1], b2[2],
                                 wsb, (float*)d_out);
}

// Round 3
// 548.386 us; speedup vs baseline: 1.0238x; 1.0238x over previous
//
#include <hip/hip_runtime.h>

typedef __attribute__((ext_vector_type(8))) short short8;
typedef __attribute__((ext_vector_type(4))) short short4v;
typedef __attribute__((ext_vector_type(4))) float floatx4;
typedef __attribute__((ext_vector_type(4))) unsigned int uintx4;

__device__ __forceinline__ short f2bf(float f) {
    unsigned u = __builtin_bit_cast(unsigned, f);
    u = (u + 0x7FFFu + ((u >> 16) & 1u)) >> 16;
    return (short)u;
}

// ---------------------------------------------------------------------------
// Workspace layout (ushort elements):
//   w1T0=0, w1T1=65536, w1T2=196608, w2T0=458752, w2T1=524288, w2T2=589824
//   xg0=655360 (4096x256), xg1=1703936 (4096x512), xg2=3801088 (4096x1024)
//   LUT0=7995392 (16384 short), LUT1=8011776 (4096), LUT2=8015872 (1024)
//   total 8,016,896 ushort = 16.03 MB
// ---------------------------------------------------------------------------
#define W1T0 0
#define W1T1 65536
#define W1T2 196608
#define W2T0 458752
#define W2T1 524288
#define W2T2 589824
#define XG0  655360
#define XG1  1703936
#define XG2  3801088
#define LUT0 7995392
#define LUT1 8011776
#define LUT2 8015872

// ---------------------------------------------------------------------------
// prep: blocks 0..639 transpose+convert weights; block 640 builds the
// position->patch LUTs (pid duplicates: one winner survives; mlp reads
// A-rows through the LUT so losers are never dereferenced).
// ---------------------------------------------------------------------------
__global__ __launch_bounds__(256) void prep(
    const float* __restrict__ w10, const float* __restrict__ w11, const float* __restrict__ w12,
    const float* __restrict__ w20, const float* __restrict__ w21, const float* __restrict__ w22,
    const int* __restrict__ p0, const int* __restrict__ p1, const int* __restrict__ p2,
    unsigned short* __restrict__ wsb)
{
    int blk = blockIdx.x;
    int t = threadIdx.x;
    if (blk == 640) {
        short* lut = (short*)(wsb + LUT0);
        for (int i = t; i < 21504; i += 256) lut[i] = -1;
        __syncthreads();
        if (t < 256) {
            ((short*)(wsb + LUT0))[p0[t]] = (short)t;
            ((short*)(wsb + LUT1))[p1[t]] = (short)t;
            ((short*)(wsb + LUT2))[p2[t]] = (short)t;
        }
        return;
    }
    __shared__ float tile[32][33];
    const float* in; unsigned short* out; int K, t0;
    if (blk < 64)       { in = w10; out = wsb + W1T0; K = 256;  t0 = 0; }
    else if (blk < 192) { in = w11; out = wsb + W1T1; K = 512;  t0 = 64; }
    else if (blk < 448) { in = w12; out = wsb + W1T2; K = 1024; t0 = 192; }
    else if (blk < 512) { in = w20; out = wsb + W2T0; K = 256;  t0 = 448; }
    else if (blk < 576) { in = w21; out = wsb + W2T1; K = 256;  t0 = 512; }
    else                { in = w22; out = wsb + W2T2; K = 256;  t0 = 576; }
    int tile_id = blk - t0;
    int tk = K >> 5;
    int k0 = (tile_id % tk) << 5;
    int n0 = (tile_id / tk) << 5;
    int j = t & 31, i0 = (t >> 5) << 2;
    #pragma unroll
    for (int u = 0; u < 4; u++)
        tile[i0 + u][j] = in[(size_t)(k0 + i0 + u) * 256 + (n0 + j)];
    __syncthreads();
    int kf = t & 31, nf0 = (t >> 5) << 2;
    #pragma unroll
    for (int u = 0; u < 4; u++)
        out[(size_t)(n0 + nf0 + u) * K + (k0 + kf)] = (unsigned short)f2bf(tile[kf][nf0 + u]);
}

// ---------------------------------------------------------------------------
// stage: blocks [0,512) random-gather scale0 (1.6% density -> random beats
// stream); blocks [512,1536) LUT-scan feat1 streamed; [1536,2048) scan feat2.
// Scan: coalesced float4 reads, LUT match, collect in LDS [256p][40c-stride],
// write matched rows as 64B aligned chunks. Latency-bound gather blocks
// overlap BW-bound scan blocks inside one kernel.
// ---------------------------------------------------------------------------
__global__ __launch_bounds__(256) void stage(
    const float* __restrict__ f0, const float* __restrict__ f1, const float* __restrict__ f2,
    const int* __restrict__ p0,
    unsigned short* __restrict__ wsb)
{
    __shared__ unsigned short tile[256 * 40];
    __shared__ int flags[256];
    int blk = blockIdx.x;
    int t = threadIdx.x;

    if (blk < 512) {
        int q = (blk << 8) + t;
        int row = q >> 5, c0 = (q & 31) << 3;
        int b = row >> 8, pp = row & 255;
        int s = p0[pp];
        const float* src = f0 + ((size_t)b * 256 + c0) * 16384 + s;
        float v[8];
        #pragma unroll
        for (int j = 0; j < 8; j++) v[j] = src[(size_t)j * 16384];
        short8 sv;
        #pragma unroll
        for (int j = 0; j < 8; j++) sv[j] = f2bf(v[j]);
        *(short8*)(wsb + XG0 + (size_t)row * 256 + c0) = sv;
        return;
    }

    const float* feat; const short* lut; unsigned short* xg;
    int C, HW, b, c0, hw0;
    if (blk < 1536) {
        int idx = blk - 512;
        feat = f1; lut = (const short*)(wsb + LUT1); xg = wsb + XG1;
        C = 512; HW = 4096;
        b = idx >> 6; int rem = idx & 63;
        c0 = (rem >> 2) << 5; hw0 = (rem & 3) << 10;
    } else {
        int idx = blk - 1536;
        feat = f2; lut = (const short*)(wsb + LUT2); xg = wsb + XG2;
        C = 1024; HW = 1024;
        b = idx >> 5; c0 = (idx & 31) << 5; hw0 = 0;
    }
    flags[t] = 0;
    __syncthreads();

    int cl = t >> 3, sub = t & 7;
    const float* fr = feat + ((size_t)b * C + c0 + cl) * HW + hw0;
    const short* lr = lut + hw0;
    for (int i = 0; i < 32; i++) {
        int hw = i * 32 + sub * 4;
        floatx4 v = *(const floatx4*)(fr + hw);
        short4v l4 = *(const short4v*)(lr + hw);
        #pragma unroll
        for (int j = 0; j < 4; j++) {
            int pv = l4[j];
            if (pv >= 0) {
                tile[pv * 40 + cl] = (unsigned short)f2bf(v[j]);
                flags[pv] = 1;
            }
        }
    }
    __syncthreads();
    if (flags[t]) {
        uintx4* d = (uintx4*)(xg + (size_t)(b * 256 + t) * C + c0);
        const uintx4* s4 = (const uintx4*)(tile + t * 40);
        d[0] = s4[0]; d[1] = s4[1]; d[2] = s4[2]; d[3] = s4[3];
    }
}

// ---------------------------------------------------------------------------
// mlp: 768 blocks (scale2 first), 16 rows x 256 cols per block, 4 waves
// (wave w = cols w*64). A and B fragments read DIRECTLY from global (L2-hot,
// 16 rows x 64B per frag-load) -- no LDS weight staging, no K-loop barriers.
// A-rows resolved through LUT (pid duplicate indirection). h hand-off via
// LDS (2 barriers total). Epilogue: bias + L2-normalize.
// ---------------------------------------------------------------------------
__global__ __launch_bounds__(256) void mlp(
    const float* __restrict__ b1_0, const float* __restrict__ b1_1, const float* __restrict__ b1_2,
    const float* __restrict__ b2_0, const float* __restrict__ b2_1, const float* __restrict__ b2_2,
    const int* __restrict__ p0, const int* __restrict__ p1, const int* __restrict__ p2,
    const unsigned short* __restrict__ wsb,
    float* __restrict__ out)
{
    __shared__ __align__(16) unsigned short hs[16 * 264];
    __shared__ float rs[16];

    int blk = blockIdx.x;
    int scale = 2 - (blk >> 8);
    int mblk = blk & 255;

    const float *b1, *b2; const int* pid;
    const unsigned short *w1T, *w2T, *xg; const short* lut;
    int C; size_t outBase;
    if (scale == 0)      { b1 = b1_0; b2 = b2_0; pid = p0; lut = (const short*)(wsb + LUT0);
                           w1T = wsb + W1T0; w2T = wsb + W2T0; xg = wsb + XG0; C = 256;  outBase = 0; }
    else if (scale == 1) { b1 = b1_1; b2 = b2_1; pid = p1; lut = (const short*)(wsb + LUT1);
                           w1T = wsb + W1T1; w2T = wsb + W2T1; xg = wsb + XG1; C = 512;  outBase = 1048576; }
    else                 { b1 = b1_2; b2 = b2_2; pid = p2; lut = (const short*)(wsb + LUT2);
                           w1T = wsb + W1T2; w2T = wsb + W2T2; xg = wsb + XG2; C = 1024; outBase = 2097152; }

    int t = threadIdx.x, wid = t >> 6, lane = t & 63, quad = lane >> 4, l15 = lane & 15;
    int c0 = wid << 6;
    int rowBase = mblk << 4;
    int myRow = rowBase + l15;
    int b = myRow >> 8, pp = myRow & 255;
    int w = lut[pid[pp]];                      // duplicate-pid indirection
    const unsigned short* aBase = xg + (size_t)(b * 256 + w) * C;

    floatx4 acc[4];
    #pragma unroll
    for (int f = 0; f < 4; f++) acc[f] = (floatx4){0.f, 0.f, 0.f, 0.f};

    // ---------------- GEMM1: x[16,C] @ w1[C,256] ----------------
    for (int kc = 0; kc < C; kc += 64) {
        short8 a0 = *(const short8*)(aBase + kc + quad * 8);
        short8 a1 = *(const short8*)(aBase + kc + 32 + quad * 8);
        #pragma unroll
        for (int f = 0; f < 4; f++) {
            const unsigned short* wr = w1T + (size_t)(c0 + f * 16 + l15) * C + kc;
            short8 bv0 = *(const short8*)(wr + quad * 8);
            short8 bv1 = *(const short8*)(wr + 32 + quad * 8);
            acc[f] = __builtin_amdgcn_mfma_f32_16x16x32_bf16(a0, bv0, acc[f], 0, 0, 0);
            acc[f] = __builtin_amdgcn_mfma_f32_16x16x32_bf16(a1, bv1, acc[f], 0, 0, 0);
        }
    }

    // ---------------- h = relu(acc + b1) -> LDS ----------------
    #pragma unroll
    for (int f = 0; f < 4; f++) {
        float bias = b1[c0 + f * 16 + l15];
        #pragma unroll
        for (int r = 0; r < 4; r++) {
            float h = fmaxf(acc[f][r] + bias, 0.f);
            hs[(quad * 4 + r) * 264 + (c0 + f * 16 + l15)] = (unsigned short)f2bf(h);
        }
    }
    if (t < 16) rs[t] = 0.f;
    __syncthreads();

    // ---------------- GEMM2: h[16,256] @ w2[256,256] ----------------
    #pragma unroll
    for (int f = 0; f < 4; f++) acc[f] = (floatx4){0.f, 0.f, 0.f, 0.f};
    const unsigned short* hA = hs + l15 * 264;
    for (int kc = 0; kc < 256; kc += 64) {
        short8 a0 = *(const short8*)(hA + kc + quad * 8);
        short8 a1 = *(const short8*)(hA + kc + 32 + quad * 8);
        #pragma unroll
        for (int f = 0; f < 4; f++) {
            const unsigned short* wr = w2T + (size_t)(c0 + f * 16 + l15) * 256 + kc;
            short8 bv0 = *(const short8*)(wr + quad * 8);
            short8 bv1 = *(const short8*)(wr + 32 + quad * 8);
            acc[f] = __builtin_amdgcn_mfma_f32_16x16x32_bf16(a0, bv0, acc[f], 0, 0, 0);
            acc[f] = __builtin_amdgcn_mfma_f32_16x16x32_bf16(a1, bv1, acc[f], 0, 0, 0);
        }
    }

    // ---------------- epilogue: y = acc + b2; y / (||y|| + 1e-7) ----------------
    float bias2[4];
    #pragma unroll
    for (int f = 0; f < 4; f++) bias2[f] = b2[c0 + f * 16 + l15];
    float psq[4] = {0.f, 0.f, 0.f, 0.f};
    #pragma unroll
    for (int f = 0; f < 4; f++)
        #pragma unroll
        for (int r = 0; r < 4; r++) {
            float yv = acc[f][r] + bias2[f];
            acc[f][r] = yv;
            psq[r] += yv * yv;
        }
    #pragma unroll
    for (int m = 1; m < 16; m <<= 1)
        #pragma unroll
        for (int r = 0; r < 4; r++)
            psq[r] += __shfl_xor(psq[r], m, 16);
    if (l15 == 0) {
        #pragma unroll
        for (int r = 0; r < 4; r++)
            atomicAdd(&rs[quad * 4 + r], psq[r]);
    }
    __syncthreads();

    #pragma unroll
    for (int f = 0; f < 4; f++)
        #pragma unroll
        for (int r = 0; r < 4; r++) {
            int row = quad * 4 + r;
            float inv = 1.f / (sqrtf(rs[row]) + 1e-7f);
            out[outBase + (size_t)(rowBase + row) * 256 + (c0 + f * 16 + l15)] =
                acc[f][r] * inv;
        }
}

extern "C" void kernel_launch(void* const* d_in, const int* in_sizes, int n_in,
                              void* d_out, int out_size, void* d_ws, size_t ws_size,
                              hipStream_t stream)
{
    (void)n_in; (void)out_size; (void)ws_size;
    bool dict = (in_sizes[1] == 256);
    const float *feat[3], *w1[3], *b1[3], *w2[3], *b2[3];
    const int* pid[3];
    for (int i = 0; i < 3; i++) {
        if (dict) {
            feat[i] = (const float*)d_in[i * 6 + 0];
            pid[i]  = (const int*)  d_in[i * 6 + 1];
            w1[i]   = (const float*)d_in[i * 6 + 2];
            b1[i]   = (const float*)d_in[i * 6 + 3];
            w2[i]   = (const float*)d_in[i * 6 + 4];
            b2[i]   = (const float*)d_in[i * 6 + 5];
        } else {
            feat[i] = (const float*)d_in[i];
            pid[i]  = (const int*)  d_in[3 + i];
            w1[i]   = (const float*)d_in[6 + 4 * i + 0];
            b1[i]   = (const float*)d_in[6 + 4 * i + 1];
            w2[i]   = (const float*)d_in[6 + 4 * i + 2];
            b2[i]   = (const float*)d_in[6 + 4 * i + 3];
        }
    }
    unsigned short* wsb = (unsigned short*)d_ws;
    prep<<<641, 256, 0, stream>>>(w1[0], w1[1], w1[2], w2[0], w2[1], w2[2],
                                  pid[0], pid[1], pid[2], wsb);
    stage<<<2048, 256, 0, stream>>>(feat[0], feat[1], feat[2], pid[0], wsb);
    mlp<<<768, 256, 0, stream>>>(b1[0], b1[1], b1[2],
                                 b2[0], b2[1], b2[2],
                                 pid[0], pid[1], pid[2],
                                 wsb, (float*)d_out);
}